// Round 1
// 288.439 us; speedup vs baseline: 1.0236x; 1.0236x over previous
//
#include <hip/hip_runtime.h>
#include <hip/hip_bf16.h>
#include <math.h>

// Problem constants
#define C_DIM 256
#define BD    128   // B*D
#define HW    784   // H*W = K
#define CN    128
#define KPAD  832   // 26 k-tiles of 32; rows = 1664 B = 13 x 128 B (line-aligned)
#define KTILES 26

typedef short bf16x8 __attribute__((ext_vector_type(8)));
typedef float f32x4 __attribute__((ext_vector_type(4)));

// fp32 -> bf16 RNE
__device__ inline ushort f2b(float f) {
  unsigned u = __float_as_uint(f);
  unsigned r = (u + 0x7FFFu + ((u >> 16) & 1u)) >> 16;
  return (ushort)r;
}

// ---------------------------------------------------------------------------
// prep_kernel: merged LN+transpose (x) and cc-convert. grid 3712, block 256.
//   blocks 0..2047  : cc fp32 -> bf16 [C][CN][KPAD] + zero K-pad (no norms --
//                     K3 derives all norms from MFMA diagonals now).
//   blocks 2048..   : LayerNorm over C + transpose -> bf16 xre [C][BD][KPAD].
// LN path: depth-2 load pipeline (8 float4 in flight vs 4), norms/atomics
// removed, LDS swizzle extended to xr2 = (l&12)|((l&3)<<4) so transpose
// writes spread over all 32 banks (was 8 -> 4-way conflict on every write).
// Same bijection on zero-fill and read side; 4-element blocks preserved.
// ---------------------------------------------------------------------------
__global__ __launch_bounds__(256, 4) void prep_kernel(
    const float* __restrict__ x, const float* __restrict__ lnw,
    const float* __restrict__ lnb, const float* __restrict__ cc,
    ushort* __restrict__ xre, ushort* __restrict__ ccb) {
  __shared__ __align__(16) ushort btile[256 * 64];   // 32 KB (ln path only)
  const int t = threadIdx.x, bid = blockIdx.x;
  const int w = t >> 6, lane = t & 63;
  const int q = lane >> 4, l = lane & 15;

  if (bid < 2048) {
    // ---------------- cc convert path ----------------
    const int c = bid >> 3;
    const int r = (bid & 7) * 16 + w * 4 + q;
    const float4* src = (const float4*)(cc + ((size_t)c * CN + r) * HW);
    ushort* dst = ccb + ((size_t)c * CN + r) * KPAD;
    float4 v[13];
#pragma unroll
    for (int i = 0; i < 13; ++i) {
      if (i < 12 || l < 4) v[i] = src[i * 16 + l];   // f<196 <=> i<12 || l<4
    }
#pragma unroll
    for (int i = 0; i < 13; ++i) {
      if (i < 12 || l < 4) {
        ushort4 o;
        o.x = f2b(v[i].x); o.y = f2b(v[i].y);
        o.z = f2b(v[i].z); o.w = f2b(v[i].w);
        *(ushort4*)(dst + (i * 16 + l) * 4) = o;
      }
    }
    if (l < 12) *(ushort4*)(dst + 784 + l * 4) = make_ushort4(0, 0, 0, 0);
    return;
  }

  // ---------------- LN + transpose path ----------------
  const int idx = bid - 2048;
  const int bx = idx % 13;
  const int bd = idx / 13;
  const int hw0 = bx * 64;
  const bool last = (bx == 12);
  const int ngroups = last ? 1 : 4;
  const int rpw = ngroups * 4;
  // full-spread swizzle: bank gets c[5:4] (bits 3:2) AND c[3:2] (bits 5:4)
  const int xr2 = (l & 12) | ((l & 3) << 4);         // f(c) for c=s*64+l*4+j
  if (last) {  // zero slots for rows 16..63 under the same per-channel bijection
    int xf = ((t >> 2) & 12) ^ ((t & 12) << 2);
    for (int r = 16; r < 64; r += 4)
      *(ushort4*)&btile[t * 64 + (r ^ xf)] = make_ushort4(0, 0, 0, 0);
  }
  float4 wv[4], bv[4];
#pragma unroll
  for (int s = 0; s < 4; ++s) {
    wv[s] = *(const float4*)(lnw + s * 64 + l * 4);
    bv[s] = *(const float4*)(lnb + s * 64 + l * 4);
  }
  const float* xb = x + ((size_t)bd * HW + hw0) * 256 + l * 4;

#define LOADG(V, g)                                                            \
  do {                                                                         \
    int r_ = w * rpw + (g) * 4 + q;                                            \
    _Pragma("unroll") for (int s = 0; s < 4; ++s)                              \
        V[s] = *(const float4*)(xb + (size_t)r_ * 256 + s * 64);               \
  } while (0)

#define PROC(V, g)                                                             \
  do {                                                                         \
    int r_ = w * rpw + (g) * 4 + q;                                            \
    float sum = 0.f, sq = 0.f;                                                 \
    _Pragma("unroll") for (int s = 0; s < 4; ++s) {                            \
      sum += V[s].x + V[s].y + V[s].z + V[s].w;                                \
      sq = fmaf(V[s].x, V[s].x, sq); sq = fmaf(V[s].y, V[s].y, sq);            \
      sq = fmaf(V[s].z, V[s].z, sq); sq = fmaf(V[s].w, V[s].w, sq);            \
    }                                                                          \
    for (int off = 1; off <= 8; off <<= 1) {                                   \
      sum += __shfl_xor(sum, off, 64);                                         \
      sq  += __shfl_xor(sq, off, 64);                                          \
    }                                                                          \
    float mu = sum * (1.f / 256.f);                                            \
    float var = fmaf(-mu, mu, sq * (1.f / 256.f));                             \
    float sc = rsqrtf(var + 1e-5f);                                            \
    int rp_ = r_ ^ xr2;                                                        \
    _Pragma("unroll") for (int s = 0; s < 4; ++s) {                            \
      float y0 = (V[s].x - mu) * sc * wv[s].x + bv[s].x;                       \
      float y1 = (V[s].y - mu) * sc * wv[s].y + bv[s].y;                       \
      float y2 = (V[s].z - mu) * sc * wv[s].z + bv[s].z;                       \
      float y3 = (V[s].w - mu) * sc * wv[s].w + bv[s].w;                       \
      int c_ = s * 64 + l * 4;                                                 \
      btile[(c_ + 0) * 64 + rp_] = f2b(y0);                                    \
      btile[(c_ + 1) * 64 + rp_] = f2b(y1);                                    \
      btile[(c_ + 2) * 64 + rp_] = f2b(y2);                                    \
      btile[(c_ + 3) * 64 + rp_] = f2b(y3);                                    \
    }                                                                          \
  } while (0)

  // depth-2 software pipeline: next group's 4 loads fly over current reduce
  float4 va[4], vb[4];
  LOADG(va, 0);
  if (ngroups > 1) {
    LOADG(vb, 1);
    PROC(va, 0);
    LOADG(va, 2);
    PROC(vb, 1);
    LOADG(vb, 3);
    PROC(va, 2);
    PROC(vb, 3);
  } else {
    PROC(va, 0);
  }
#undef LOADG
#undef PROC
  __syncthreads();
  // write-out: uint2/lane; 4 channels x 128 B aligned per instruction
#pragma unroll
  for (int i = 0; i < 16; ++i) {
    int c = w * 64 + i * 4 + (lane >> 4);
    int xw = ((c >> 2) & 12) ^ ((c & 12) << 2);      // per-instr constant
    int ho = (lane & 15) * 4;
    uint2 val = *(const uint2*)&btile[c * 64 + (ho ^ xw)];
    *(uint2*)(xre + (size_t)c * (BD * KPAD) + (size_t)bd * KPAD + hw0 + ho) = val;
  }
}

// ---------------------------------------------------------------------------
// K3: fused MFMA GEMM-dist. grid 256 (one block per c), 512 threads (8 waves).
// Stage xre[c] (At) and ccb[c] (Bt) k-tiles ONCE; compute
//   D_x = A.B^T (dist + in-register softmax)  and  D_c = B.B^T.
// Norms are now derived IN-KERNEL from MFMA diagonals (no anorm/bnorm pass):
//   ||b_p||^2 = diag(B.B^T) -> already inside accc[w];
//   ||a_p||^2 = diag(A.A^T) -> one extra mfma(af,af) per k-tile per wave.
// This makes d2 = ||a||^2+||b||^2-2ab EXACT in bf16-value space (cluster_dist
// diagonal cancels to 0 identically), so accuracy improves vs fp32 norms.
// Diag values exchanged through a 1 KB LDS buffer. Double-buffered staging,
// issue-after-barrier, XOR chunk swizzle as before.
// ---------------------------------------------------------------------------
__global__ __launch_bounds__(512) void gemm_fused_kernel(
    const ushort* __restrict__ xre, const ushort* __restrict__ ccb,
    float* __restrict__ out_d, float* __restrict__ out_s,
    float* __restrict__ out_c) {
  __shared__ __align__(16) ushort At[2][4096];  // 128 rows x 32 k
  __shared__ __align__(16) ushort Bt[2][4096];
  __shared__ float an_l[128], bn_l[128];
  const int c = blockIdx.x;
  const int t = threadIdx.x, w = t >> 6, lane = t & 63;
  const int quad = lane >> 4, ln = lane & 15;
  const ushort* Ag = xre + (size_t)c * (128 * KPAD);
  const ushort* Bg = ccb + (size_t)c * (128 * KPAD);

  f32x4 accx[8], accc[8];
  f32x4 accd = f32x4{0.f, 0.f, 0.f, 0.f};
  for (int j = 0; j < 8; ++j) {
    accx[j] = f32x4{0.f, 0.f, 0.f, 0.f};
    accc[j] = f32x4{0.f, 0.f, 0.f, 0.f};
  }

  // staging: thread t covers chunk ci = t of the 128x32 tile
  const int srow = t >> 2, scq = (t & 3) ^ (srow & 3);
  const ushort* gA = Ag + (size_t)srow * KPAD + scq * 8;
  const ushort* gB = Bg + (size_t)srow * KPAD + scq * 8;

  // LDS fragment offsets (ushort units), computed once
  const int m = w * 16 + ln;
  const int aoff = (m * 4 + (quad ^ (m & 3))) * 8;   // row m of At / Bt
  int boff[8];
#pragma unroll
  for (int j = 0; j < 8; ++j) {
    int n = j * 16 + ln;
    boff[j] = (n * 4 + (quad ^ (n & 3))) * 8;
  }

#define ISSUE(k, p)                                                            \
  do {                                                                         \
    int kb = (k) * 32;                                                         \
    __builtin_amdgcn_global_load_lds(                                          \
        (const __attribute__((address_space(1))) unsigned int*)(gA + kb),      \
        (__attribute__((address_space(3))) unsigned int*)&At[p][t * 8], 16, 0, 0); \
    __builtin_amdgcn_global_load_lds(                                          \
        (const __attribute__((address_space(1))) unsigned int*)(gB + kb),      \
        (__attribute__((address_space(3))) unsigned int*)&Bt[p][t * 8], 16, 0, 0); \
  } while (0)

  ISSUE(0, 0);
  for (int k0 = 0; k0 < KTILES; ++k0) {
    __syncthreads();
    if (k0 < KTILES - 1) ISSUE(k0 + 1, (k0 + 1) & 1);
    const int p = k0 & 1;
    bf16x8 af = *(const bf16x8*)&At[p][aoff];   // x_re row m
    bf16x8 ar = *(const bf16x8*)&Bt[p][aoff];   // cc row m (same offset formula)
    accd = __builtin_amdgcn_mfma_f32_16x16x32_bf16(af, af, accd, 0, 0, 0);
#pragma unroll
    for (int j = 0; j < 8; ++j) {
      bf16x8 bfj = *(const bf16x8*)&Bt[p][boff[j]];
      accx[j] = __builtin_amdgcn_mfma_f32_16x16x32_bf16(af, bfj, accx[j], 0, 0, 0);
      accc[j] = __builtin_amdgcn_mfma_f32_16x16x32_bf16(ar, bfj, accc[j], 0, 0, 0);
    }
  }
#undef ISSUE

  // publish diagonals: D[m'][n'] lives at lane (quad=m'>>2, ln=n'), reg r=m'&3.
  // Diagonal element p (=quad*4+r==ln) held where (ln>>2)==quad.
  if ((ln >> 2) == quad) {
    an_l[w * 16 + ln] = accd[ln & 3];       // ||a_{w*16+ln}||^2
    bn_l[w * 16 + ln] = accc[w][ln & 3];    // ||b_{w*16+ln}||^2
  }
  __syncthreads();

  float cn[8];
  for (int j = 0; j < 8; ++j) cn[j] = bn_l[j * 16 + ln];
  float rx[4], rc[4];
  for (int r = 0; r < 4; ++r) {
    int p16 = quad * 4 + r;
    rx[r] = an_l[w * 16 + p16];
    rc[r] = bn_l[w * 16 + p16];
  }
  // cluster_dist
  for (int r = 0; r < 4; ++r) {
    int mr = w * 16 + quad * 4 + r;
    float* ob = out_c + (size_t)c * (128 * 128) + (size_t)mr * 128;
    for (int j = 0; j < 8; ++j) {
      float d2 = rc[r] + cn[j] - 2.f * accc[j][r];
      ob[j * 16 + ln] = sqrtf(fmaxf(d2, 1e-12f));
    }
  }
  // x_distance + softmax (row fully in-quad: 8 regs x 16 ln)
  for (int r = 0; r < 4; ++r) {
    int mr = w * 16 + quad * 4 + r;
    float dr[8];
    for (int j = 0; j < 8; ++j) {
      float d2 = rx[r] + cn[j] - 2.f * accx[j][r];
      dr[j] = sqrtf(fmaxf(d2, 1e-12f));
    }
    float* ob = out_d + ((size_t)mr * 256 + c) * 128;
    for (int j = 0; j < 8; ++j) ob[j * 16 + ln] = dr[j];
    float mn = dr[0];
    for (int j = 1; j < 8; ++j) mn = fminf(mn, dr[j]);
    for (int off = 1; off <= 8; off <<= 1) mn = fminf(mn, __shfl_xor(mn, off, 64));
    float e[8], s = 0.f;
    for (int j = 0; j < 8; ++j) { e[j] = __expf(-32.f * (dr[j] - mn)); s += e[j]; }
    for (int off = 1; off <= 8; off <<= 1) s += __shfl_xor(s, off, 64);
    float inv = 1.f / s;
    float* os = out_s + ((size_t)mr * 256 + c) * 128;
    for (int j = 0; j < 8; ++j) os[j * 16 + ln] = e[j] * inv;
  }
}

extern "C" void kernel_launch(void* const* d_in, const int* in_sizes, int n_in,
                              void* d_out, int out_size, void* d_ws, size_t ws_size,
                              hipStream_t stream) {
  const float* x   = (const float*)d_in[0];
  const float* lnw = (const float*)d_in[1];
  const float* lnb = (const float*)d_in[2];
  const float* cc  = (const float*)d_in[3];
  float* out   = (float*)d_out;
  float* out_d = out;             // x_distance        [8,16,256,128]
  float* out_s = out + 4194304;   // x_distance_assign [8,16,256,128]
  float* out_c = out + 8388608;   // cluster_dist      [256,128,128]

  ushort* xre_b = (ushort*)d_ws;              // 256*128*832 bf16 = 54.5 MB
  ushort* cc_b  = xre_b + 27262976;           // 54.5 MB

  // one merged prep launch: 2048 cc-convert blocks + 1664 LN-transpose blocks
  prep_kernel<<<3712, 256, 0, stream>>>(x, lnw, lnb, cc, xre_b, cc_b);
  gemm_fused_kernel<<<256, 512, 0, stream>>>(xre_b, cc_b, out_d, out_s, out_c);
}